// Round 4
// baseline (460.045 us; speedup 1.0000x reference)
//
#include <hip/hip_runtime.h>
#include <math.h>

// N=4, S=2048, D=1024, fp32 in/out.
// Pipeline (ALL GEMMs are GLL-staged f16-plane MFMA; conversion happens once in a pre-pass):
//   split   : q,k -> hi/lo planes ; v,WV -> hi ; WQ,WK -> hi/lo
//   qk-proj : ONE 256^2 triple GLL GEMM (big_gemm DUAL), M=16384 folds q|k, EPI_SPLIT out
//   wvT = (v@WVt)^T        : single-product GLL GEMM (128^2 template), f16 hi transposed out
//   Sc = wq@wkt            : 256^2 triple GLL GEMM (big_gemm), single-barrier loop,
//                            XCD-chunked mapping, f32 out + fused column stats
//   combine                : fold 8 q-chunk partials -> m[k], r[k]=1/sum
//   pmat                   : P_hi = (f16) exp(Sc - m[k]) * r[k]
//   out = (P @ wvT^T)/1024 : single-product GLL GEMM (128^2 template), f32 out
// Workspace (f16 units, NSD = 8388608, DD = 1048576; peak < 10*NSD budget):
//   [0,1)N      q_hi   ; later wvT_hi (q dead after qk-proj)
//   [1,2)N      q_lo   ; later Sc f32 spans [1,5)N (q_lo/k/v dead by then)
//   [2,4)N      k_hi|k_lo
//   [4,5)N      v_hi
//   [5N,5N+5DD) WQ_hi|WQ_lo|WK_hi|WK_lo|WV_hi
//   [5N+5DD, 9N+5DD) wq_hi|wq_lo|wk_hi|wk_lo ; later P_hi aliases wq_hi..(2N)
//   [9N+5DD, ..) stats (pm|ps|statM|statR, ~0.6 MB)

typedef _Float16 f16;
typedef _Float16 f16x8 __attribute__((ext_vector_type(8)));
typedef _Float16 f16x4 __attribute__((ext_vector_type(4)));
typedef float f32x4 __attribute__((ext_vector_type(4)));

enum StageMode { SM_PLANES2, SM_PLANES1 };
enum EpiMode   { EPI_F32, EPI_SPLIT, EPI_F16T };

#define GLL_PITCH 32   // f16 units/row; unpadded, XOR-swizzled 16B chunks

// async global->LDS, 16B per lane; LDS dest = wave-uniform base + lane*16
__device__ __forceinline__ void gll16(const f16* g, f16* l) {
    __builtin_amdgcn_global_load_lds(
        (const __attribute__((address_space(1))) void*)g,
        (__attribute__((address_space(3))) void*)l, 16, 0, 0);
}

// Stage one 128x32 f16 plane via GLL with XOR chunk swizzle (4-wave version, old template).
// Physical 16B slot t holds data (row = t>>2, chunk = (t&3) ^ ((row>>1)&3)).
__device__ __forceinline__ void stage_gll_plane(const f16* __restrict__ gplane,
                                                f16* __restrict__ lds,
                                                long rowBase, int ld, int k0,
                                                int wave, int lane)
{
#pragma unroll
    for (int i = 0; i < 2; i++) {
        int slotBase = (wave * 2 + i) * 64;
        int t = slotBase + lane;
        int r = t >> 2;
        int c = (t & 3) ^ ((r >> 1) & 3);
        const f16* g = gplane + (rowBase + r) * (long)ld + k0 + c * 8;
        gll16(g, lds + (long)slotBase * 8);   // wave-uniform LDS base
    }
}

__device__ __forceinline__ int frag_off_gll(int row, int g) {
    return row * GLL_PITCH + ((g ^ ((row >> 1) & 3)) << 3);
}

// ---------------------------------------------------------------------------
// Old 128x128 template (v-projection + final GEMM).
// C = A * B^T. A: [M,K], B: [Nc,K] row-major f16 planes (per batch plane).
// Tile 128x128, BK=32, 256 threads = 4 waves, each wave 64x64 (4x4 of 16x16x32).
template<StageMode SA, StageMode SB, EpiMode EP, int GROUPM, bool STATS>
__global__ __launch_bounds__(256, 4)
void mfma_gemm(const f16* __restrict__ Ahi, const f16* __restrict__ Alo,
               const f16* __restrict__ Bhi, const f16* __restrict__ Blo,
               float* __restrict__ pmOut, float* __restrict__ psOut,
               void* __restrict__ C0, void* __restrict__ C1,
               int M, int Nc, int K, int lda, int ldb, int ldc,
               long batchA, long batchB, long batchC,
               float epiScale, int tsShift)
{
    constexpr bool TRIPLE = (SA == SM_PLANES2);
    constexpr int PLANE_SZ = 128 * GLL_PITCH;

    int bx, by;
    if constexpr (GROUPM > 0) {
        int gx = gridDim.x;
        int lin = blockIdx.y * gx + blockIdx.x;
        int nig = GROUPM * gx;
        int gid = lin / nig;
        int rem = lin - gid * nig;
        by = gid * GROUPM + (rem % GROUPM);
        bx = rem / GROUPM;
    } else {
        bx = blockIdx.x;
        by = blockIdx.y;
    }
    const int n0 = bx * 128;
    const int m0 = by * 128;
    const long z = blockIdx.z;

    const long aOfs = z * batchA, bOfs = z * batchB, cOfs = z * batchC;

    __shared__ __align__(16) f16 As_hi[PLANE_SZ];
    __shared__ __align__(16) f16 Bs_hi[PLANE_SZ];
    __shared__ __align__(16) f16 As_lo[TRIPLE ? PLANE_SZ : 8];
    __shared__ __align__(16) f16 Bs_lo[TRIPLE ? PLANE_SZ : 8];

    const int tid  = threadIdx.x;
    const int lane = tid & 63;
    const int wave = tid >> 6;
    const int wr = (wave >> 1) * 64;
    const int wc = (wave & 1) * 64;
    const int fm = lane & 15;
    const int fg = lane >> 4;        // k-chunk index 0..3

    f32x4 acc[4][4];
#pragma unroll
    for (int i = 0; i < 4; i++)
#pragma unroll
        for (int j = 0; j < 4; j++) acc[i][j] = (f32x4){0.f, 0.f, 0.f, 0.f};

    int roA[4], roB[4];
#pragma unroll
    for (int i = 0; i < 4; i++) {
        roA[i] = frag_off_gll(wr + i * 16 + fm, fg);
        roB[i] = frag_off_gll(wc + i * 16 + fm, fg);
    }

    for (int k0 = 0; k0 < K; k0 += 32) {
        stage_gll_plane(Ahi + aOfs, As_hi, m0, lda, k0, wave, lane);
        stage_gll_plane(Bhi + bOfs, Bs_hi, n0, ldb, k0, wave, lane);
        if constexpr (TRIPLE) {
            stage_gll_plane(Alo + aOfs, As_lo, m0, lda, k0, wave, lane);
            stage_gll_plane(Blo + bOfs, Bs_lo, n0, ldb, k0, wave, lane);
        }
        __syncthreads();

        f16x8 ah[4], bh[4], al[4], bl[4];
#pragma unroll
        for (int i = 0; i < 4; i++) {
            ah[i] = *(const f16x8*)&As_hi[roA[i]];
            bh[i] = *(const f16x8*)&Bs_hi[roB[i]];
            if constexpr (TRIPLE) {
                al[i] = *(const f16x8*)&As_lo[roA[i]];
                bl[i] = *(const f16x8*)&Bs_lo[roB[i]];
            }
        }
#pragma unroll
        for (int i = 0; i < 4; i++) {
#pragma unroll
            for (int j = 0; j < 4; j++) {
                acc[i][j] = __builtin_amdgcn_mfma_f32_16x16x32_f16(ah[i], bh[j], acc[i][j], 0, 0, 0);
                if constexpr (TRIPLE) {
                    acc[i][j] = __builtin_amdgcn_mfma_f32_16x16x32_f16(ah[i], bl[j], acc[i][j], 0, 0, 0);
                    acc[i][j] = __builtin_amdgcn_mfma_f32_16x16x32_f16(al[i], bh[j], acc[i][j], 0, 0, 0);
                }
            }
        }
        __syncthreads();
    }

    // Epilogue. C/D frag: col = lane&15, row = (lane>>4)*4 + reg  [m89-verified]
    const int cr = fg * 4;
    const int cn = fm;
#pragma unroll
    for (int i = 0; i < 4; i++) {
#pragma unroll
        for (int j = 0; j < 4; j++) {
#pragma unroll
            for (int r = 0; r < 4; r++) {
                long mg = m0 + wr + i * 16 + cr + r;
                long ng = n0 + wc + j * 16 + cn;
                float val = acc[i][j][r] * epiScale;
                if constexpr (EP == EPI_F32) {
                    ((float*)C0)[cOfs + mg * ldc + ng] = val;
                } else if constexpr (EP == EPI_SPLIT) {
                    f16 h = (f16)val;
                    ((f16*)C0)[cOfs + mg * ldc + ng] = h;
                    ((f16*)C1)[cOfs + mg * ldc + ng] = (f16)(val - (float)h);
                } else { // EPI_F16T: batch folded in M; write [nb][n][s], hi only
                    long TS = 1L << tsShift;
                    long nb = mg >> tsShift;
                    long s  = mg & (TS - 1);
                    long addr = nb * ((long)Nc << tsShift) + ng * TS + s;
                    ((f16*)C0)[addr] = (f16)val;
                }
            }
        }
    }

    if constexpr (STATS) {
        __shared__ float stM[2][128];
        __shared__ float stS[2][128];
#pragma unroll
        for (int j = 0; j < 4; j++) {
            float mj = -3.402823466e38f;
#pragma unroll
            for (int i = 0; i < 4; i++)
#pragma unroll
                for (int r = 0; r < 4; r++) mj = fmaxf(mj, acc[i][j][r]);
            float sj = 0.f;
#pragma unroll
            for (int i = 0; i < 4; i++)
#pragma unroll
                for (int r = 0; r < 4; r++) sj += __expf(acc[i][j][r] - mj);
#pragma unroll
            for (int mask = 16; mask <= 32; mask <<= 1) {
                float mo = __shfl_xor(mj, mask, 64);
                float so = __shfl_xor(sj, mask, 64);
                float mn = fmaxf(mj, mo);
                sj = sj * __expf(mj - mn) + so * __expf(mo - mn);
                mj = mn;
            }
            if (fg == 0) {
                stM[wave >> 1][wc + j * 16 + cn] = mj;
                stS[wave >> 1][wc + j * 16 + cn] = sj;
            }
        }
        __syncthreads();
        if (tid < 128) {
            float ma = stM[0][tid], mb = stM[1][tid];
            float Mc = fmaxf(ma, mb);
            float Sv = stS[0][tid] * __expf(ma - Mc) + stS[1][tid] * __expf(mb - Mc);
            long o = ((long)z * (M >> 7) + by) * (long)Nc + (long)bx * 128 + tid;
            pmOut[o] = Mc;
            psOut[o] = Sv;
        }
    }
}

// ---------------------------------------------------------------------------
// 256x256 triple-product GEMM (scores + combined q/k projection).
// C = A @ B^T, f16 hi/lo split planes, BK=32, 512 threads = 8 waves (2Mx4N),
// per-wave 128x64. Single barrier per K-tile:
//   vmcnt(0)  — drains THIS wave's stage(t) loads, issued one full tile ago
//   s_barrier — publishes ALL waves' stage(t) LDS writes (vmcnt precedes it)
//   stage(t+1) into buf^1 — its reads were consumed last iter (lgkm drained
//                            by MFMA data deps), so no second barrier needed;
//                            GLL LDS-writes proceed under this tile's MFMA
//   interleaved ds_reads + 3 MFMA clusters on buf cur
// DUAL mode: blocks with by >= msplitTiles switch to the second A/B/C set
// (k-projection with WK) — folds both projections into one 256-block dispatch.
// XCDMAP (scores): XCD j owns all 8 bx x 4 (by,z) pairs -> each A panel on one XCD.
template<EpiMode EP, bool STATS, bool XCDMAP, bool DUAL>
__global__ __launch_bounds__(512, 2)
void big_gemm(const f16* __restrict__ Ahi, const f16* __restrict__ Alo,
              const f16* __restrict__ Bhi, const f16* __restrict__ Blo,
              const f16* __restrict__ A2hi, const f16* __restrict__ A2lo,
              const f16* __restrict__ B2hi, const f16* __restrict__ B2lo,
              float* __restrict__ pmOut, float* __restrict__ psOut,
              void* __restrict__ C0, void* __restrict__ C1,
              void* __restrict__ C20, void* __restrict__ C21,
              int M, int Nc, int K, int lda, int ldb, int ldc,
              long batchA, long batchB, long batchC, int msplitTiles)
{
    constexpr int PLANE = 256 * GLL_PITCH;   // 8192 f16 = 16 KB

    __shared__ __align__(16) f16 As_hi[2][PLANE];
    __shared__ __align__(16) f16 As_lo[2][PLANE];
    __shared__ __align__(16) f16 Bs_hi[2][PLANE];
    __shared__ __align__(16) f16 Bs_lo[2][PLANE];

    const int tid  = threadIdx.x;
    const int lane = tid & 63;
    const int wave = tid >> 6;
    const int rw   = wave >> 2;      // 0..1 : row half (128 rows)
    const int cw   = wave & 3;       // 0..3 : col quarter (64 cols)
    const int wrM  = rw * 128;
    const int wrN  = cw * 64;
    const int fm   = lane & 15;
    const int fg   = lane >> 4;      // k-chunk index 0..3

    int bxn, byn, zn;
    if constexpr (XCDMAP) {
        // grid (8,8,4) = 256 blocks, 1/CU; HW round-robins linear%8 across XCDs.
        const int Lid = (int)(blockIdx.z * 64 + blockIdx.y * 8 + blockIdx.x);
        const int xcd = Lid & 7;
        const int sct = Lid >> 3;
        bxn = sct & 7;
        const int idxp = xcd * 4 + (sct >> 3);
        byn = idxp & 7;
        zn  = idxp >> 3;
    } else {
        bxn = blockIdx.x;
        byn = blockIdx.y;
        zn  = blockIdx.z;
    }

    const f16* pAhi = Ahi; const f16* pAlo = Alo;
    const f16* pBhi = Bhi; const f16* pBlo = Blo;
    void* pC0 = C0; void* pC1 = C1;
    int mTile = byn;
    if constexpr (DUAL) {
        if (byn >= msplitTiles) {
            pAhi = A2hi; pAlo = A2lo; pBhi = B2hi; pBlo = B2lo;
            pC0 = C20; pC1 = C21;
            mTile = byn - msplitTiles;
        }
    }

    const int n0 = bxn * 256;
    const int m0 = mTile * 256;
    const long z = zn;
    const long aOfs = z * batchA, bOfs = z * batchB, cOfs = z * batchC;

    // staging: 1024 16B slots per 256x32 plane; this thread owns two.
    // slot t holds (row = t>>2, chunk = (t&3) ^ ((row>>1)&3)).
    int slotBase[2], srcA[2], srcB[2];
#pragma unroll
    for (int i = 0; i < 2; i++) {
        int sb = (wave * 2 + i) * 64;        // wave-uniform slot base
        int t  = sb + lane;
        int r  = t >> 2;
        int c  = (t & 3) ^ ((r >> 1) & 3);
        slotBase[i] = sb * 8;                // f16 units
        srcA[i] = (m0 + r) * lda + c * 8;
        srcB[i] = (n0 + r) * ldb + c * 8;
    }

#define SC_STAGE(buf, k0) do {                                               \
    _Pragma("unroll")                                                        \
    for (int s_ = 0; s_ < 2; s_++) {                                         \
        gll16(pAhi + aOfs + srcA[s_] + (k0), &As_hi[buf][slotBase[s_]]);     \
        gll16(pAlo + aOfs + srcA[s_] + (k0), &As_lo[buf][slotBase[s_]]);     \
        gll16(pBhi + bOfs + srcB[s_] + (k0), &Bs_hi[buf][slotBase[s_]]);     \
        gll16(pBlo + bOfs + srcB[s_] + (k0), &Bs_lo[buf][slotBase[s_]]);     \
    } } while (0)

    f32x4 acc[8][4];
#pragma unroll
    for (int i = 0; i < 8; i++)
#pragma unroll
        for (int j = 0; j < 4; j++) acc[i][j] = (f32x4){0.f, 0.f, 0.f, 0.f};

    int roA[8], roB[4];
#pragma unroll
    for (int i = 0; i < 8; i++) roA[i] = frag_off_gll(wrM + i * 16 + fm, fg);
#pragma unroll
    for (int j = 0; j < 4; j++) roB[j] = frag_off_gll(wrN + j * 16 + fm, fg);

    const int NT = K >> 5;     // 32 K-tiles
    SC_STAGE(0, 0);            // tile 0 -> buf 0   (8 loads)
    SC_STAGE(1, 32);           // tile 1 -> buf 1   (16 loads in flight)

    for (int t = 0; t < NT; t++) {
        const int cur = t & 1;
        // Drain MY stage(t) loads (issued one full tile ago -> aged, ~free),
        // then barrier publishes ALL waves' stage(t) LDS writes.
        if (t == 0) {
            asm volatile("s_waitcnt vmcnt(8)" ::: "memory");
        } else {
            asm volatile("s_waitcnt vmcnt(0)" ::: "memory");
        }
        __builtin_amdgcn_sched_barrier(0);
        __builtin_amdgcn_s_barrier();
        __builtin_amdgcn_sched_barrier(0);

        // Refill the buffer consumed LAST iteration (reads of it were lgkm-
        // drained by last iter's MFMA data deps before this barrier).
        if (t >= 1 && t + 1 < NT) SC_STAGE(cur ^ 1, (t + 1) * 32);
        __builtin_amdgcn_sched_barrier(0);

        // ---- issue reads in consumption order ----
        f16x8 bh[4], a0h[4];
#pragma unroll
        for (int j = 0; j < 4; j++) bh[j] = *(const f16x8*)&Bs_hi[cur][roB[j]];
#pragma unroll
        for (int i = 0; i < 4; i++) a0h[i] = *(const f16x8*)&As_hi[cur][roA[i]];
        __builtin_amdgcn_sched_barrier(0);
        f16x8 bl[4], a0l[4];
#pragma unroll
        for (int j = 0; j < 4; j++) bl[j] = *(const f16x8*)&Bs_lo[cur][roB[j]];
#pragma unroll
        for (int i = 0; i < 4; i++) a0l[i] = *(const f16x8*)&As_lo[cur][roA[i]];
        __builtin_amdgcn_sched_barrier(0);

        // ---- c1: 16 MFMA (a0h x bh) ----
        __builtin_amdgcn_s_setprio(1);
#pragma unroll
        for (int i = 0; i < 4; i++)
#pragma unroll
            for (int j = 0; j < 4; j++)
                acc[i][j] = __builtin_amdgcn_mfma_f32_16x16x32_f16(a0h[i], bh[j], acc[i][j], 0, 0, 0);
        __builtin_amdgcn_s_setprio(0);
        __builtin_amdgcn_sched_barrier(0);

        // c3 inputs issued under c2's MFMA shadow
        f16x8 a1h[4], a1l[4];
#pragma unroll
        for (int i = 0; i < 4; i++) {
            a1h[i] = *(const f16x8*)&As_hi[cur][roA[4 + i]];
            a1l[i] = *(const f16x8*)&As_lo[cur][roA[4 + i]];
        }
        __builtin_amdgcn_sched_barrier(0);

        // ---- c2: 32 MFMA (a0h x bl, a0l x bh) ----
        __builtin_amdgcn_s_setprio(1);
#pragma unroll
        for (int i = 0; i < 4; i++)
#pragma unroll
            for (int j = 0; j < 4; j++)
                acc[i][j] = __builtin_amdgcn_mfma_f32_16x16x32_f16(a0h[i], bl[j], acc[i][j], 0, 0, 0);
#pragma unroll
        for (int i = 0; i < 4; i++)
#pragma unroll
            for (int j = 0; j < 4; j++)
                acc[i][j] = __builtin_amdgcn_mfma_f32_16x16x32_f16(a0l[i], bh[j], acc[i][j], 0, 0, 0);
        __builtin_amdgcn_s_setprio(0);
        __builtin_amdgcn_sched_barrier(0);

        // ---- c3: 48 MFMA (a1h x bh, a1h x bl, a1l x bh) ----
        __builtin_amdgcn_s_setprio(1);
#pragma unroll
        for (int i = 0; i < 4; i++)
#pragma unroll
            for (int j = 0; j < 4; j++)
                acc[4 + i][j] = __builtin_amdgcn_mfma_f32_16x16x32_f16(a1h[i], bh[j], acc[4 + i][j], 0, 0, 0);
#pragma unroll
        for (int i = 0; i < 4; i++)
#pragma unroll
            for (int j = 0; j < 4; j++)
                acc[4 + i][j] = __builtin_amdgcn_mfma_f32_16x16x32_f16(a1h[i], bl[j], acc[4 + i][j], 0, 0, 0);
#pragma unroll
        for (int i = 0; i < 4; i++)
#pragma unroll
            for (int j = 0; j < 4; j++)
                acc[4 + i][j] = __builtin_amdgcn_mfma_f32_16x16x32_f16(a1l[i], bh[j], acc[4 + i][j], 0, 0, 0);
        __builtin_amdgcn_s_setprio(0);
    }
#undef SC_STAGE

    // Epilogue. C/D frag: col = lane&15, row = (lane>>4)*4 + reg.
    const int cr = fg * 4;
#pragma unroll
    for (int i = 0; i < 8; i++) {
#pragma unroll
        for (int j = 0; j < 4; j++) {
#pragma unroll
            for (int r = 0; r < 4; r++) {
                long mg = m0 + wrM + i * 16 + cr + r;
                long ng = n0 + wrN + j * 16 + fm;
                float val = acc[i][j][r];
                if constexpr (EP == EPI_F32) {
                    ((float*)pC0)[cOfs + mg * (long)ldc + ng] = val;
                } else { // EPI_SPLIT
                    f16 h = (f16)val;
                    ((f16*)pC0)[cOfs + mg * (long)ldc + ng] = h;
                    ((f16*)pC1)[cOfs + mg * (long)ldc + ng] = (f16)(val - (float)h);
                }
            }
        }
    }

    // Fused column-softmax partials over this tile's 256 q-rows.
    if constexpr (STATS) {
        __shared__ float stM[2][256];
        __shared__ float stS[2][256];
#pragma unroll
        for (int j = 0; j < 4; j++) {
            float mj = -3.402823466e38f;
#pragma unroll
            for (int i = 0; i < 8; i++)
#pragma unroll
                for (int r = 0; r < 4; r++) mj = fmaxf(mj, acc[i][j][r]);
            float sj = 0.f;
#pragma unroll
            for (int i = 0; i < 8; i++)
#pragma unroll
                for (int r = 0; r < 4; r++) sj += __expf(acc[i][j][r] - mj);
#pragma unroll
            for (int mask = 16; mask <= 32; mask <<= 1) {
                float mo = __shfl_xor(mj, mask, 64);
                float so = __shfl_xor(sj, mask, 64);
                float mn = fmaxf(mj, mo);
                sj = sj * __expf(mj - mn) + so * __expf(mo - mn);
                mj = mn;
            }
            if (fg == 0) {
                stM[rw][wrN + j * 16 + fm] = mj;
                stS[rw][wrN + j * 16 + fm] = sj;
            }
        }
        __syncthreads();
        if (tid < 256) {
            float ma = stM[0][tid], mb = stM[1][tid];
            float Mc = fmaxf(ma, mb);
            float Sv = stS[0][tid] * __expf(ma - Mc) + stS[1][tid] * __expf(mb - Mc);
            long o = ((long)z * (M >> 8) + byn) * (long)Nc + (long)bxn * 256 + tid;
            pmOut[o] = Mc;
            psOut[o] = Sv;
        }
    }
}

// Elementwise f32 -> f16 hi (+ optional lo) split. n multiple of 2048.
template<bool HAS_LO>
__global__ __launch_bounds__(256)
void split_kernel(const float* __restrict__ src, f16* __restrict__ hi,
                  f16* __restrict__ lo, long n)
{
    long i = ((long)blockIdx.x * 256 + threadIdx.x) * 8;
    if (i >= n) return;
    float4 x0 = *(const float4*)&src[i];
    float4 x1 = *(const float4*)&src[i + 4];
    float xs[8] = {x0.x, x0.y, x0.z, x0.w, x1.x, x1.y, x1.z, x1.w};
    f16x8 h, l;
#pragma unroll
    for (int e = 0; e < 8; e++) {
        f16 hh = (f16)xs[e];
        h[e] = hh;
        if (HAS_LO) l[e] = (f16)(xs[e] - (float)hh);
    }
    *(f16x8*)&hi[i] = h;
    if (HAS_LO) *(f16x8*)&lo[i] = l;
}

// Fold the CH q-chunk partials -> m[k], r[k] = 1/sum.
template<int CH>
__global__ __launch_bounds__(64)
void stats_combine_kernel(const float* __restrict__ pm, const float* __restrict__ ps,
                          float* __restrict__ statM, float* __restrict__ statR, int S)
{
    const int n = blockIdx.y;
    const int kk = blockIdx.x * 64 + threadIdx.x;
    float M = -INFINITY;
#pragma unroll
    for (int i = 0; i < CH; i++)
        M = fmaxf(M, pm[((long)n * CH + i) * S + kk]);
    float Ssum = 0.f;
#pragma unroll
    for (int i = 0; i < CH; i++)
        Ssum += ps[((long)n * CH + i) * S + kk] * __expf(pm[((long)n * CH + i) * S + kk] - M);
    statM[(long)n * S + kk] = M;
    statR[(long)n * S + kk] = 1.0f / Ssum;
}

// P_hi = (f16)(exp(Sc - m[k]) * r[k]).  Grid: (S/1024, S/32, N); thread = 4 k cols.
__global__ __launch_bounds__(256)
void pmat_kernel(const float* __restrict__ Sc, const float* __restrict__ statM,
                 const float* __restrict__ statR, f16* __restrict__ Phi, int S)
{
    const int n = blockIdx.z;
    const int kk = blockIdx.x * 1024 + threadIdx.x * 4;
    const float* Sn = Sc + (long)n * S * S;
    f16* ph = Phi + (long)n * S * S;
    float4 M4 = *(const float4*)&statM[(long)n * S + kk];
    float4 R4 = *(const float4*)&statR[(long)n * S + kk];
    const int q0 = blockIdx.y * 32;
    for (int qi = 0; qi < 32; qi++) {
        long idx = (long)(q0 + qi) * S + kk;
        float4 x = *(const float4*)&Sn[idx];
        f16x4 p;
        p[0] = (f16)(__expf(x.x - M4.x) * R4.x);
        p[1] = (f16)(__expf(x.y - M4.y) * R4.y);
        p[2] = (f16)(__expf(x.z - M4.z) * R4.z);
        p[3] = (f16)(__expf(x.w - M4.w) * R4.w);
        *(f16x4*)&ph[idx] = p;
    }
}

extern "C" void kernel_launch(void* const* d_in, const int* in_sizes, int n_in,
                              void* d_out, int out_size, void* d_ws, size_t ws_size,
                              hipStream_t stream)
{
    const float* v  = (const float*)d_in[0];
    const float* k  = (const float*)d_in[1];
    const float* q  = (const float*)d_in[2];
    const float* WV = (const float*)d_in[3];
    const float* WQ = (const float*)d_in[4];
    const float* WK = (const float*)d_in[5];
    float* out = (float*)d_out;

    const int N = 4, S = 2048, D = 1024;
    const long NSD = (long)N * S * D;   // 8388608
    const long DD  = (long)D * D;       // 1048576

    f16* ws = (f16*)d_ws;
    // phase-1 buffers
    f16* q_hi = ws;                 // [0,1)N
    f16* q_lo = ws + NSD;           // [1,2)N
    f16* k_hi = ws + 2 * NSD;
    f16* k_lo = ws + 3 * NSD;
    f16* v_hi = ws + 4 * NSD;
    f16* Wb   = ws + 5 * NSD;       // weight planes
    f16* WQ_hi = Wb,          *WQ_lo = Wb + DD;
    f16* WK_hi = Wb + 2 * DD, *WK_lo = Wb + 3 * DD;
    f16* WV_hi = Wb + 4 * DD;
    // projection outputs
    f16* wq_hi = ws + 5 * NSD + 5 * DD;
    f16* wq_lo = wq_hi + NSD;
    f16* wk_hi = wq_hi + 2 * NSD;
    f16* wk_lo = wq_hi + 3 * NSD;
    // aliases (lifetime-checked):
    f16* wvT_hi = ws;                       // [0,1)N — q_hi dead after qk-proj
    float* Sc   = (float*)(ws + NSD);       // [1,5)N — q_lo/k/v dead by scores
    f16* P_hi   = wq_hi;                    // wq/wk dead after scores
    // stats: pm/ps are [N][8][S] (256^2 scores tile => 8 q-chunks)
    float* pm    = (float*)(ws + 9 * NSD + 5 * DD);
    float* ps    = pm + (long)N * 8 * S;
    float* statM = ps + (long)N * 8 * S;
    float* statR = statM + (long)N * S;

    dim3 blk(256);

    // ---- split pre-pass ----
    split_kernel<true ><<<dim3(NSD / 2048), blk, 0, stream>>>(q,  q_hi, q_lo, NSD);
    split_kernel<true ><<<dim3(NSD / 2048), blk, 0, stream>>>(k,  k_hi, k_lo, NSD);
    split_kernel<false><<<dim3(NSD / 2048), blk, 0, stream>>>(v,  v_hi, nullptr, NSD);
    split_kernel<true ><<<dim3(DD / 2048),  blk, 0, stream>>>(WQ, WQ_hi, WQ_lo, DD);
    split_kernel<true ><<<dim3(DD / 2048),  blk, 0, stream>>>(WK, WK_hi, WK_lo, DD);
    split_kernel<false><<<dim3(DD / 2048),  blk, 0, stream>>>(WV, WV_hi, nullptr, DD);

    // ---- q+k projections combined: ONE 256-block dispatch (big_gemm DUAL) ----
    // M = 2*N*S folded: by<32 -> q@WQ^T -> wq ; by>=32 -> k@WK^T -> wk.
    // Natural grid (4,64): each XCD gets one 256-col weight strip (L2-resident).
    {
        dim3 g(D / 256, (2 * N * S) / 256, 1);   // (4, 64)
        big_gemm<EPI_SPLIT, false, false, true><<<g, dim3(512), 0, stream>>>(
            q_hi, q_lo, WQ_hi, WQ_lo,
            k_hi, k_lo, WK_hi, WK_lo,
            nullptr, nullptr,
            wq_hi, wq_lo, wk_hi, wk_lo,
            2 * N * S, D, D, D, D, D, 0, 0, 0, (N * S) / 256 /* 32 */);
    }
    // ---- v projection: wvT = (v@WVt)^T, old 128^2 template ----
    {
        dim3 g(D / 128, (N * S) / 128, 1);
        mfma_gemm<SM_PLANES1, SM_PLANES1, EPI_F16T, 4, false><<<g, blk, 0, stream>>>(
            v_hi, nullptr, WV_hi, nullptr, nullptr, nullptr, wvT_hi, nullptr,
            N * S, D, D, D, D, 0, 0, 0, 0, 1.0f, 11 /* tsShift: S=2048 */);
    }
    // ---- scores: Sc[n] = wq[n] @ wk[n]^T (f32) + fused column-stat partials ----
    {
        dim3 g(S / 256, S / 256, N);
        big_gemm<EPI_F32, true, true, false><<<g, dim3(512), 0, stream>>>(
            wq_hi, wq_lo, wk_hi, wk_lo,
            nullptr, nullptr, nullptr, nullptr,
            pm, ps, Sc, nullptr, nullptr, nullptr,
            S, S, D, D, D, S, (long)S * D, (long)S * D, (long)S * S, 1 << 30);
    }
    // ---- combine partials -> statM, statR ----
    {
        dim3 gB(S / 64, N);
        stats_combine_kernel<8><<<gB, dim3(64), 0, stream>>>(pm, ps, statM, statR, S);
    }
    // ---- P_hi = exp(Sc - m)*r ----
    {
        dim3 g(S / 1024, S / 32, N);
        pmat_kernel<<<g, blk, 0, stream>>>(Sc, statM, statR, P_hi, S);
    }
    // ---- out[n] = (P[n] @ wvT[n]^T) / 1024 ----
    {
        dim3 g(D / 128, S / 128, N);
        mfma_gemm<SM_PLANES1, SM_PLANES1, EPI_F32, 4, false><<<g, blk, 0, stream>>>(
            P_hi, nullptr, wvT_hi, nullptr, nullptr, nullptr, out, nullptr,
            S, D, S, S, S, D, (long)S * S, (long)S * D, (long)S * D, 1.0f / (float)D, 0);
    }
}

// Round 7
// 438.659 us; speedup vs baseline: 1.0488x; 1.0488x over previous
//
#include <hip/hip_runtime.h>
#include <math.h>

// N=4, S=2048, D=1024, fp32 in/out.
// Pipeline (ALL GEMMs are GLL-staged f16-plane MFMA; conversion happens once in a pre-pass):
//   split_all : ONE dispatch — q,k -> hi/lo ; v -> hi ; WQ,WK -> hi/lo ; WV -> hi
//   qk-proj : big_gemm DUAL (256^2, 8-wave, single-barrier depth-2) — ROUND-4 VERIFIED
//   wvT = (v@WVt)^T        : single-product GLL GEMM (128^2 template), f16 hi transposed
//   Sc = wq@wkt            : big_gemm XCDMAP (256^2) — ROUND-4 VERIFIED, f32 + stats
//   pmat    : folds the 8-chunk stats combine + P_hi = (f16) exp(Sc - m[k]) * r[k]
//   out = (P @ wvT^T)/1024 : single-product GLL GEMM (128^2 template), f32 out
// 7 dispatches total (was 13; ~10 us/launch measured gap).
// Workspace (f16 units, NSD = 8388608, DD = 1048576; peak < 10*NSD budget):
//   [0,1)N q_hi (later wvT_hi) | [1,2)N q_lo (later Sc f32 [1,5)N) | [2,4)N k_hi|k_lo
//   [4,5)N v_hi | [5N,5N+5DD) weights | [5N+5DD,9N+5DD) wq|wk planes (later P_hi)
//   [9N+5DD,..) stats pm|ps [N][8][S]

typedef _Float16 f16;
typedef _Float16 f16x8 __attribute__((ext_vector_type(8)));
typedef _Float16 f16x4 __attribute__((ext_vector_type(4)));
typedef float f32x4 __attribute__((ext_vector_type(4)));

enum StageMode { SM_PLANES2, SM_PLANES1 };
enum EpiMode   { EPI_F32, EPI_SPLIT, EPI_F16T };

#define GLL_PITCH 32   // f16 units/row; unpadded, XOR-swizzled 16B chunks

// async global->LDS, 16B per lane; LDS dest = wave-uniform base + lane*16
__device__ __forceinline__ void gll16(const f16* g, f16* l) {
    __builtin_amdgcn_global_load_lds(
        (const __attribute__((address_space(1))) void*)g,
        (__attribute__((address_space(3))) void*)l, 16, 0, 0);
}

// Stage one 128x32 f16 plane via GLL with XOR chunk swizzle (4-wave version).
__device__ __forceinline__ void stage_gll_plane(const f16* __restrict__ gplane,
                                                f16* __restrict__ lds,
                                                long rowBase, int ld, int k0,
                                                int wave, int lane)
{
#pragma unroll
    for (int i = 0; i < 2; i++) {
        int slotBase = (wave * 2 + i) * 64;
        int t = slotBase + lane;
        int r = t >> 2;
        int c = (t & 3) ^ ((r >> 1) & 3);
        const f16* g = gplane + (rowBase + r) * (long)ld + k0 + c * 8;
        gll16(g, lds + (long)slotBase * 8);   // wave-uniform LDS base
    }
}

__device__ __forceinline__ int frag_off_gll(int row, int g) {
    return row * GLL_PITCH + ((g ^ ((row >> 1) & 3)) << 3);
}

// ---------------------------------------------------------------------------
// 128x128 16x16x32 template (v-projection + final GEMM). Verified.
template<StageMode SA, StageMode SB, EpiMode EP, int GROUPM, bool STATS>
__global__ __launch_bounds__(256, 4)
void mfma_gemm(const f16* __restrict__ Ahi, const f16* __restrict__ Alo,
               const f16* __restrict__ Bhi, const f16* __restrict__ Blo,
               float* __restrict__ pmOut, float* __restrict__ psOut,
               void* __restrict__ C0, void* __restrict__ C1,
               int M, int Nc, int K, int lda, int ldb, int ldc,
               long batchA, long batchB, long batchC,
               float epiScale, int tsShift)
{
    constexpr bool TRIPLE = (SA == SM_PLANES2);
    constexpr int PLANE_SZ = 128 * GLL_PITCH;

    int bx, by;
    if constexpr (GROUPM > 0) {
        int gx = gridDim.x;
        int lin = blockIdx.y * gx + blockIdx.x;
        int nig = GROUPM * gx;
        int gid = lin / nig;
        int rem = lin - gid * nig;
        by = gid * GROUPM + (rem % GROUPM);
        bx = rem / GROUPM;
    } else {
        bx = blockIdx.x;
        by = blockIdx.y;
    }
    const int n0 = bx * 128;
    const int m0 = by * 128;
    const long z = blockIdx.z;

    const long aOfs = z * batchA, bOfs = z * batchB, cOfs = z * batchC;

    __shared__ __align__(16) f16 As_hi[PLANE_SZ];
    __shared__ __align__(16) f16 Bs_hi[PLANE_SZ];
    __shared__ __align__(16) f16 As_lo[TRIPLE ? PLANE_SZ : 8];
    __shared__ __align__(16) f16 Bs_lo[TRIPLE ? PLANE_SZ : 8];

    const int tid  = threadIdx.x;
    const int lane = tid & 63;
    const int wave = tid >> 6;
    const int wr = (wave >> 1) * 64;
    const int wc = (wave & 1) * 64;
    const int fm = lane & 15;
    const int fg = lane >> 4;

    f32x4 acc[4][4];
#pragma unroll
    for (int i = 0; i < 4; i++)
#pragma unroll
        for (int j = 0; j < 4; j++) acc[i][j] = (f32x4){0.f, 0.f, 0.f, 0.f};

    int roA[4], roB[4];
#pragma unroll
    for (int i = 0; i < 4; i++) {
        roA[i] = frag_off_gll(wr + i * 16 + fm, fg);
        roB[i] = frag_off_gll(wc + i * 16 + fm, fg);
    }

    for (int k0 = 0; k0 < K; k0 += 32) {
        stage_gll_plane(Ahi + aOfs, As_hi, m0, lda, k0, wave, lane);
        stage_gll_plane(Bhi + bOfs, Bs_hi, n0, ldb, k0, wave, lane);
        if constexpr (TRIPLE) {
            stage_gll_plane(Alo + aOfs, As_lo, m0, lda, k0, wave, lane);
            stage_gll_plane(Blo + bOfs, Bs_lo, n0, ldb, k0, wave, lane);
        }
        __syncthreads();

        f16x8 ah[4], bh[4], al[4], bl[4];
#pragma unroll
        for (int i = 0; i < 4; i++) {
            ah[i] = *(const f16x8*)&As_hi[roA[i]];
            bh[i] = *(const f16x8*)&Bs_hi[roB[i]];
            if constexpr (TRIPLE) {
                al[i] = *(const f16x8*)&As_lo[roA[i]];
                bl[i] = *(const f16x8*)&Bs_lo[roB[i]];
            }
        }
#pragma unroll
        for (int i = 0; i < 4; i++) {
#pragma unroll
            for (int j = 0; j < 4; j++) {
                acc[i][j] = __builtin_amdgcn_mfma_f32_16x16x32_f16(ah[i], bh[j], acc[i][j], 0, 0, 0);
                if constexpr (TRIPLE) {
                    acc[i][j] = __builtin_amdgcn_mfma_f32_16x16x32_f16(ah[i], bl[j], acc[i][j], 0, 0, 0);
                    acc[i][j] = __builtin_amdgcn_mfma_f32_16x16x32_f16(al[i], bh[j], acc[i][j], 0, 0, 0);
                }
            }
        }
        __syncthreads();
    }

    // Epilogue. C/D frag: col = lane&15, row = (lane>>4)*4 + reg  [m89-verified]
    const int cr = fg * 4;
    const int cn = fm;
#pragma unroll
    for (int i = 0; i < 4; i++) {
#pragma unroll
        for (int j = 0; j < 4; j++) {
#pragma unroll
            for (int r = 0; r < 4; r++) {
                long mg = m0 + wr + i * 16 + cr + r;
                long ng = n0 + wc + j * 16 + cn;
                float val = acc[i][j][r] * epiScale;
                if constexpr (EP == EPI_F32) {
                    ((float*)C0)[cOfs + mg * ldc + ng] = val;
                } else if constexpr (EP == EPI_SPLIT) {
                    f16 h = (f16)val;
                    ((f16*)C0)[cOfs + mg * ldc + ng] = h;
                    ((f16*)C1)[cOfs + mg * ldc + ng] = (f16)(val - (float)h);
                } else { // EPI_F16T: batch folded in M; write [nb][n][s], hi only
                    long TS = 1L << tsShift;
                    long nb = mg >> tsShift;
                    long s  = mg & (TS - 1);
                    long addr = nb * ((long)Nc << tsShift) + ng * TS + s;
                    ((f16*)C0)[addr] = (f16)val;
                }
            }
        }
    }
}

// ---------------------------------------------------------------------------
// ROUND-4 VERIFIED big_gemm: 256x256 tile, 8 waves (2Mx4N) of 128x64, 16x16x32
// triple product, BK=32, depth-2 counted-vmcnt single-barrier loop.
// XCDMAP (scores): grid (8,8,4); DUAL: byn >= msplitTiles -> second problem.
template<EpiMode EP, bool STATS, bool XCDMAP, bool DUAL>
__global__ __launch_bounds__(512, 2)
void big_gemm(const f16* __restrict__ Ahi, const f16* __restrict__ Alo,
              const f16* __restrict__ Bhi, const f16* __restrict__ Blo,
              const f16* __restrict__ A2hi, const f16* __restrict__ A2lo,
              const f16* __restrict__ B2hi, const f16* __restrict__ B2lo,
              float* __restrict__ pmOut, float* __restrict__ psOut,
              void* __restrict__ C0, void* __restrict__ C1,
              void* __restrict__ C20, void* __restrict__ C21,
              int M, int Nc, int K, int lda, int ldb, int ldc,
              long batchA, long batchB, long batchC, int msplitTiles)
{
    constexpr int PLANE = 256 * GLL_PITCH;   // 8192 f16 = 16 KB

    __shared__ __align__(16) f16 As_hi[2][PLANE];
    __shared__ __align__(16) f16 As_lo[2][PLANE];
    __shared__ __align__(16) f16 Bs_hi[2][PLANE];
    __shared__ __align__(16) f16 Bs_lo[2][PLANE];

    const int tid  = threadIdx.x;
    const int lane = tid & 63;
    const int wave = tid >> 6;
    const int rw   = wave >> 2;      // 0..1 : row half (128 rows)
    const int cw   = wave & 3;       // 0..3 : col quarter (64 cols)
    const int wrM  = rw * 128;
    const int wrN  = cw * 64;
    const int fm   = lane & 15;
    const int fg   = lane >> 4;      // k-chunk index 0..3

    int bxn, byn, zn;
    if constexpr (XCDMAP) {
        // grid (8,8,4) = 256 blocks, 1/CU; HW round-robins linear%8 across XCDs.
        const int Lid = (int)(blockIdx.z * 64 + blockIdx.y * 8 + blockIdx.x);
        const int xcd = Lid & 7;
        const int sct = Lid >> 3;
        bxn = sct & 7;
        const int idxp = xcd * 4 + (sct >> 3);
        byn = idxp & 7;
        zn  = idxp >> 3;
    } else {
        bxn = blockIdx.x;
        byn = blockIdx.y;
        zn  = blockIdx.z;
    }

    const f16* pAhi = Ahi; const f16* pAlo = Alo;
    const f16* pBhi = Bhi; const f16* pBlo = Blo;
    void* pC0 = C0; void* pC1 = C1;
    int mTile = byn;
    if constexpr (DUAL) {
        if (byn >= msplitTiles) {
            pAhi = A2hi; pAlo = A2lo; pBhi = B2hi; pBlo = B2lo;
            pC0 = C20; pC1 = C21;
            mTile = byn - msplitTiles;
        }
    }

    const int n0 = bxn * 256;
    const int m0 = mTile * 256;
    const long z = zn;
    const long aOfs = z * batchA, bOfs = z * batchB, cOfs = z * batchC;

    // staging: 1024 16B slots per 256x32 plane; this thread owns two.
    int slotBase[2], srcA[2], srcB[2];
#pragma unroll
    for (int i = 0; i < 2; i++) {
        int sb = (wave * 2 + i) * 64;        // wave-uniform slot base
        int t  = sb + lane;
        int r  = t >> 2;
        int c  = (t & 3) ^ ((r >> 1) & 3);
        slotBase[i] = sb * 8;                // f16 units
        srcA[i] = (m0 + r) * lda + c * 8;
        srcB[i] = (n0 + r) * ldb + c * 8;
    }

#define SC_STAGE(buf, k0) do {                                               \
    _Pragma("unroll")                                                        \
    for (int s_ = 0; s_ < 2; s_++) {                                         \
        gll16(pAhi + aOfs + srcA[s_] + (k0), &As_hi[buf][slotBase[s_]]);     \
        gll16(pAlo + aOfs + srcA[s_] + (k0), &As_lo[buf][slotBase[s_]]);     \
        gll16(pBhi + bOfs + srcB[s_] + (k0), &Bs_hi[buf][slotBase[s_]]);     \
        gll16(pBlo + bOfs + srcB[s_] + (k0), &Bs_lo[buf][slotBase[s_]]);     \
    } } while (0)

    f32x4 acc[8][4];
#pragma unroll
    for (int i = 0; i < 8; i++)
#pragma unroll
        for (int j = 0; j < 4; j++) acc[i][j] = (f32x4){0.f, 0.f, 0.f, 0.f};

    int roA[8], roB[4];
#pragma unroll
    for (int i = 0; i < 8; i++) roA[i] = frag_off_gll(wrM + i * 16 + fm, fg);
#pragma unroll
    for (int j = 0; j < 4; j++) roB[j] = frag_off_gll(wrN + j * 16 + fm, fg);

    const int NT = K >> 5;     // 32 K-tiles
    SC_STAGE(0, 0);            // tile 0 -> buf 0   (8 loads)
    SC_STAGE(1, 32);           // tile 1 -> buf 1   (16 loads in flight)

    for (int t = 0; t < NT; t++) {
        const int cur = t & 1;
        // Drain MY stage(t) loads (issued one full tile ago -> aged),
        // then barrier publishes ALL waves' stage(t) LDS writes.
        if (t == 0) {
            asm volatile("s_waitcnt vmcnt(8)" ::: "memory");
        } else {
            asm volatile("s_waitcnt vmcnt(0)" ::: "memory");
        }
        __builtin_amdgcn_sched_barrier(0);
        __builtin_amdgcn_s_barrier();
        __builtin_amdgcn_sched_barrier(0);

        // Refill the buffer consumed LAST iteration (reads were lgkm-drained
        // by last iter's MFMA data deps before this barrier).
        if (t >= 1 && t + 1 < NT) SC_STAGE(cur ^ 1, (t + 1) * 32);
        __builtin_amdgcn_sched_barrier(0);

        // ---- issue reads in consumption order ----
        f16x8 bh[4], a0h[4];
#pragma unroll
        for (int j = 0; j < 4; j++) bh[j] = *(const f16x8*)&Bs_hi[cur][roB[j]];
#pragma unroll
        for (int i = 0; i < 4; i++) a0h[i] = *(const f16x8*)&As_hi[cur][roA[i]];
        __builtin_amdgcn_sched_barrier(0);
        f16x8 bl[4], a0l[4];
#pragma unroll
        for (int j = 0; j < 4; j++) bl[j] = *(const f16x8*)&Bs_lo[cur][roB[j]];
#pragma unroll
        for (int i = 0; i < 4; i++) a0l[i] = *(const f16x8*)&As_lo[cur][roA[i]];
        __builtin_amdgcn_sched_barrier(0);

        // ---- c1: 16 MFMA (a0h x bh) ----
        __builtin_amdgcn_s_setprio(1);
#pragma unroll
        for (int i = 0; i < 4; i++)
#pragma unroll
            for (int j = 0; j < 4; j++)
                acc[i][j] = __builtin_amdgcn_mfma_f32_16x16x32_f16(a0h[i], bh[j], acc[i][j], 0, 0, 0);
        __builtin_amdgcn_s_setprio(0);
        __builtin_amdgcn_sched_barrier(0);

        // c3 inputs issued under c2's MFMA shadow
        f16x8 a1h[4], a1l[4];
#pragma unroll
        for (int i = 0; i < 4; i++) {
            a1h[i] = *(const f16x8*)&As_hi[cur][roA[4 + i]];
            a1l[i] = *(const f16x8*)&As_lo[cur][roA[4 + i]];
        }
        __builtin_amdgcn_sched_barrier(0);

        // ---- c2: 32 MFMA (a0h x bl, a0l x bh) ----
        __builtin_amdgcn_s_setprio(1);
#pragma unroll
        for (int i = 0; i < 4; i++)
#pragma unroll
            for (int j = 0; j < 4; j++)
                acc[i][j] = __builtin_amdgcn_mfma_f32_16x16x32_f16(a0h[i], bl[j], acc[i][j], 0, 0, 0);
#pragma unroll
        for (int i = 0; i < 4; i++)
#pragma unroll
            for (int j = 0; j < 4; j++)
                acc[i][j] = __builtin_amdgcn_mfma_f32_16x16x32_f16(a0l[i], bh[j], acc[i][j], 0, 0, 0);
        __builtin_amdgcn_s_setprio(0);
        __builtin_amdgcn_sched_barrier(0);

        // ---- c3: 48 MFMA (a1h x bh, a1h x bl, a1l x bh) ----
        __builtin_amdgcn_s_setprio(1);
#pragma unroll
        for (int i = 0; i < 4; i++)
#pragma unroll
            for (int j = 0; j < 4; j++)
                acc[4 + i][j] = __builtin_amdgcn_mfma_f32_16x16x32_f16(a1h[i], bh[j], acc[4 + i][j], 0, 0, 0);
#pragma unroll
        for (int i = 0; i < 4; i++)
#pragma unroll
            for (int j = 0; j < 4; j++)
                acc[4 + i][j] = __builtin_amdgcn_mfma_f32_16x16x32_f16(a1h[i], bl[j], acc[4 + i][j], 0, 0, 0);
#pragma unroll
        for (int i = 0; i < 4; i++)
#pragma unroll
            for (int j = 0; j < 4; j++)
                acc[4 + i][j] = __builtin_amdgcn_mfma_f32_16x16x32_f16(a1l[i], bh[j], acc[4 + i][j], 0, 0, 0);
        __builtin_amdgcn_s_setprio(0);
    }
#undef SC_STAGE

    // Epilogue. C/D frag: col = lane&15, row = (lane>>4)*4 + reg.
    const int cr = fg * 4;
#pragma unroll
    for (int i = 0; i < 8; i++) {
#pragma unroll
        for (int j = 0; j < 4; j++) {
#pragma unroll
            for (int r = 0; r < 4; r++) {
                long mg = m0 + wrM + i * 16 + cr + r;
                long ng = n0 + wrN + j * 16 + fm;
                float val = acc[i][j][r];
                if constexpr (EP == EPI_F32) {
                    ((float*)pC0)[cOfs + mg * (long)ldc + ng] = val;
                } else { // EPI_SPLIT
                    f16 h = (f16)val;
                    ((f16*)pC0)[cOfs + mg * (long)ldc + ng] = h;
                    ((f16*)pC1)[cOfs + mg * (long)ldc + ng] = (f16)(val - (float)h);
                }
            }
        }
    }

    // Fused column-softmax partials over this tile's 256 q-rows.
    if constexpr (STATS) {
        __shared__ float stM[2][256];
        __shared__ float stS[2][256];
#pragma unroll
        for (int j = 0; j < 4; j++) {
            float mj = -3.402823466e38f;
#pragma unroll
            for (int i = 0; i < 8; i++)
#pragma unroll
                for (int r = 0; r < 4; r++) mj = fmaxf(mj, acc[i][j][r]);
            float sj = 0.f;
#pragma unroll
            for (int i = 0; i < 8; i++)
#pragma unroll
                for (int r = 0; r < 4; r++) sj += __expf(acc[i][j][r] - mj);
#pragma unroll
            for (int mask = 16; mask <= 32; mask <<= 1) {
                float mo = __shfl_xor(mj, mask, 64);
                float so = __shfl_xor(sj, mask, 64);
                float mn = fmaxf(mj, mo);
                sj = sj * __expf(mj - mn) + so * __expf(mo - mn);
                mj = mn;
            }
            if (fg == 0) {
                stM[rw][wrN + j * 16 + fm] = mj;
                stS[rw][wrN + j * 16 + fm] = sj;
            }
        }
        __syncthreads();
        if (tid < 256) {
            float ma = stM[0][tid], mb = stM[1][tid];
            float Mc = fmaxf(ma, mb);
            float Sv = stS[0][tid] * __expf(ma - Mc) + stS[1][tid] * __expf(mb - Mc);
            long o = ((long)z * (M >> 8) + byn) * (long)Nc + (long)bxn * 256 + tid;
            pmOut[o] = Mc;
            psOut[o] = Sv;
        }
    }
}

// ---------------------------------------------------------------------------
// ONE-dispatch split pre-pass: f32 -> f16 hi (+lo) for all six tensors.
// Region select is block-uniform (branch on blockIdx.x ranges).
__global__ __launch_bounds__(256)
void split_all_kernel(const float* __restrict__ q, const float* __restrict__ k,
                      const float* __restrict__ v, const float* __restrict__ WQ,
                      const float* __restrict__ WK, const float* __restrict__ WV,
                      f16* __restrict__ ws, long NSD, long DD)
{
    const long QB = NSD / 2048;   // blocks per q/k/v region
    const long WB = DD / 2048;    // blocks per weight region
    const long b = blockIdx.x;
    f16* Wb = ws + 5 * NSD;

    const float* src;
    f16* hi;
    f16* lo = nullptr;
    long base;
    if (b < QB)               { src = q;  base = b * 2048;                 hi = ws;           lo = ws + NSD;   }
    else if (b < 2 * QB)      { src = k;  base = (b - QB) * 2048;          hi = ws + 2 * NSD; lo = ws + 3 * NSD; }
    else if (b < 3 * QB)      { src = v;  base = (b - 2 * QB) * 2048;      hi = ws + 4 * NSD; }
    else if (b < 3 * QB + WB) { src = WQ; base = (b - 3 * QB) * 2048;      hi = Wb;           lo = Wb + DD;    }
    else if (b < 3 * QB + 2 * WB) { src = WK; base = (b - 3 * QB - WB) * 2048; hi = Wb + 2 * DD; lo = Wb + 3 * DD; }
    else                      { src = WV; base = (b - 3 * QB - 2 * WB) * 2048; hi = Wb + 4 * DD; }

    long i = base + (long)threadIdx.x * 8;
    float4 x0 = *(const float4*)&src[i];
    float4 x1 = *(const float4*)&src[i + 4];
    float xs[8] = {x0.x, x0.y, x0.z, x0.w, x1.x, x1.y, x1.z, x1.w};
    f16x8 h, l;
#pragma unroll
    for (int e = 0; e < 8; e++) {
        f16 hh = (f16)xs[e];
        h[e] = hh;
        l[e] = (f16)(xs[e] - (float)hh);
    }
    *(f16x8*)&hi[i] = h;
    if (lo) *(f16x8*)&lo[i] = l;
}

// ---------------------------------------------------------------------------
// pmat with FUSED stats combine: each thread folds the 8 q-chunk partials for
// its 4 columns (pm/ps are [N][8][S], 512 KB -> L2-resident; redundant reads
// across q-block rows are cheap), then P_hi = (f16)(exp(Sc - m) * r).
// Grid: (S/1024, S/32, N); thread = 4 k cols x 32 q rows.
__global__ __launch_bounds__(256)
void pmat_kernel(const float* __restrict__ Sc, const float* __restrict__ pm,
                 const float* __restrict__ ps, f16* __restrict__ Phi, int S)
{
    const int n = blockIdx.z;
    const int kk = blockIdx.x * 1024 + threadIdx.x * 4;
    const float* Sn = Sc + (long)n * S * S;
    f16* ph = Phi + (long)n * S * S;

    float M4[4], R4[4];
#pragma unroll
    for (int c = 0; c < 4; c++) {
        const int col = kk + c;
        float pmv[8];
        float M = -INFINITY;
#pragma unroll
        for (int i = 0; i < 8; i++) {
            pmv[i] = pm[((long)n * 8 + i) * S + col];
            M = fmaxf(M, pmv[i]);
        }
        float Ssum = 0.f;
#pragma unroll
        for (int i = 0; i < 8; i++)
            Ssum += ps[((long)n * 8 + i) * S + col] * __expf(pmv[i] - M);
        M4[c] = M;
        R4[c] = 1.0f / Ssum;
    }

    const int q0 = blockIdx.y * 32;
    for (int qi = 0; qi < 32; qi++) {
        long idx = (long)(q0 + qi) * S + kk;
        float4 x = *(const float4*)&Sn[idx];
        f16x4 p;
        p[0] = (f16)(__expf(x.x - M4[0]) * R4[0]);
        p[1] = (f16)(__expf(x.y - M4[1]) * R4[1]);
        p[2] = (f16)(__expf(x.z - M4[2]) * R4[2]);
        p[3] = (f16)(__expf(x.w - M4[3]) * R4[3]);
        *(f16x4*)&ph[idx] = p;
    }
}

extern "C" void kernel_launch(void* const* d_in, const int* in_sizes, int n_in,
                              void* d_out, int out_size, void* d_ws, size_t ws_size,
                              hipStream_t stream)
{
    const float* v  = (const float*)d_in[0];
    const float* k  = (const float*)d_in[1];
    const float* q  = (const float*)d_in[2];
    const float* WV = (const float*)d_in[3];
    const float* WQ = (const float*)d_in[4];
    const float* WK = (const float*)d_in[5];
    float* out = (float*)d_out;

    const int N = 4, S = 2048, D = 1024;
    const long NSD = (long)N * S * D;   // 8388608
    const long DD  = (long)D * D;       // 1048576

    f16* ws = (f16*)d_ws;
    f16* q_hi = ws;
    f16* q_lo = ws + NSD;
    f16* k_hi = ws + 2 * NSD;
    f16* k_lo = ws + 3 * NSD;
    f16* v_hi = ws + 4 * NSD;
    f16* Wb   = ws + 5 * NSD;
    f16* WQ_hi = Wb,          *WQ_lo = Wb + DD;
    f16* WK_hi = Wb + 2 * DD, *WK_lo = Wb + 3 * DD;
    f16* WV_hi = Wb + 4 * DD;
    f16* wq_hi = ws + 5 * NSD + 5 * DD;
    f16* wq_lo = wq_hi + NSD;
    f16* wk_hi = wq_hi + 2 * NSD;
    f16* wk_lo = wq_hi + 3 * NSD;
    f16* wvT_hi = ws;                       // q_hi dead after qk-proj
    float* Sc   = (float*)(ws + NSD);       // q_lo/k/v dead by scores
    f16* P_hi   = wq_hi;                    // wq/wk dead after scores
    // stats: pm/ps are [N][8][S] (256^2 scores tile => 8 q-chunks)
    float* pm    = (float*)(ws + 9 * NSD + 5 * DD);
    float* ps    = pm + (long)N * 8 * S;

    dim3 blk(256);

    // ---- split pre-pass: ONE dispatch ----
    {
        long nblocks = 3 * (NSD / 2048) + 3 * (DD / 2048);   // 13824
        split_all_kernel<<<dim3((unsigned)nblocks), blk, 0, stream>>>(
            q, k, v, WQ, WK, WV, ws, NSD, DD);
    }

    // ---- q+k projections combined: big_gemm DUAL (round-4 verified) ----
    // M = 2*N*S folded: by<32 -> q@WQ^T -> wq ; by>=32 -> k@WK^T -> wk.
    {
        dim3 g(D / 256, (2 * N * S) / 256, 1);   // (4, 64)
        big_gemm<EPI_SPLIT, false, false, true><<<g, dim3(512), 0, stream>>>(
            q_hi, q_lo, WQ_hi, WQ_lo,
            k_hi, k_lo, WK_hi, WK_lo,
            nullptr, nullptr,
            wq_hi, wq_lo, wk_hi, wk_lo,
            2 * N * S, D, D, D, D, D, 0, 0, 0, (N * S) / 256 /* 32 */);
    }
    // ---- v projection: wvT = (v@WVt)^T, 128^2 template ----
    {
        dim3 g(D / 128, (N * S) / 128, 1);
        mfma_gemm<SM_PLANES1, SM_PLANES1, EPI_F16T, 4, false><<<g, blk, 0, stream>>>(
            v_hi, nullptr, WV_hi, nullptr, nullptr, nullptr, wvT_hi, nullptr,
            N * S, D, D, D, D, 0, 0, 0, 0, 1.0f, 11 /* tsShift: S=2048 */);
    }
    // ---- scores: Sc[n] = wq[n] @ wk[n]^T (f32) + fused column-stat partials ----
    {
        dim3 g(S / 256, S / 256, N);             // (8,8,4) = 256 blocks, XCD-chunked
        big_gemm<EPI_F32, true, true, false><<<g, dim3(512), 0, stream>>>(
            wq_hi, wq_lo, wk_hi, wk_lo,
            nullptr, nullptr, nullptr, nullptr,
            pm, ps, Sc, nullptr, nullptr, nullptr,
            S, S, D, D, D, S, (long)S * D, (long)S * D, (long)S * S, 1 << 30);
    }
    // ---- P_hi = exp(Sc - m)*r  (stats combine folded in) ----
    {
        dim3 g(S / 1024, S / 32, N);
        pmat_kernel<<<g, blk, 0, stream>>>(Sc, pm, ps, P_hi, S);
    }
    // ---- out[n] = (P[n] @ wvT[n]^T) / 1024 ----
    {
        dim3 g(D / 128, S / 128, N);
        mfma_gemm<SM_PLANES1, SM_PLANES1, EPI_F32, 4, false><<<g, blk, 0, stream>>>(
            P_hi, nullptr, wvT_hi, nullptr, nullptr, nullptr, out, nullptr,
            S, D, S, S, S, D, (long)S * S, (long)S * D, (long)S * D, 1.0f / (float)D, 0);
    }
}